// Round 6
// baseline (1561.707 us; speedup 1.0000x reference)
//
#include <hip/hip_runtime.h>
#include <stdint.h>

#define HH   128
#define NLAY 3
#define RR   32
#define OO   48
#define BBX  64
#define FFX  32
#define LLX  (RR + OO - 1)    /* 79 */
#define RBr  (RR * BBX)       /* 2048 */
#define N6   (6 * HH)         /* 768 */
#define TSTEPS (LLX + NLAY - 1)  /* 81 */
#define NBLOCKS 192

typedef unsigned short u16;
typedef __attribute__((ext_vector_type(8))) short short8;
typedef __attribute__((ext_vector_type(4))) float f32x4;

// ---- workspace layout ----
#define OFF_ABUF0 ((size_t)0)
#define SZ_ABUF0  ((size_t)LLX * RBr * FFX * 2)
#define OFF_HZ    (OFF_ABUF0 + SZ_ABUF0)
#define SZ_HZ     ((size_t)NLAY * 2 * RBr * 256 * 2)   /* [l][slot][2048][256] bf16 */
#define OFF_BAR   (OFF_HZ + SZ_HZ)
#define SZ_BAR    ((size_t)4096)   /* barG @0, barC[b] @128+b*128, table @2048 */
#define SZ_STATE  (SZ_HZ + SZ_BAR)
#define OFF_ACTV  (OFF_BAR + SZ_BAR)
#define SZ_ACTV   ((size_t)2 * 2 * RBr * 256 * 2)

__device__ __forceinline__ u16 f2b(float x) {
  uint32_t u = __float_as_uint(x);
  return (u16)((u + 0x7FFFu + ((u >> 16) & 1u)) >> 16);
}
__device__ __forceinline__ float sigmoidf_(float x) {
  return 1.0f / (1.0f + __expf(-x));
}
__device__ __forceinline__ float tanhf_(float x) {
  float e = __expf(2.0f * x);
  return 1.0f - 2.0f / (e + 1.0f);
}

__global__ __launch_bounds__(256) void k_prep_input(const float* __restrict__ inp,
                                                    u16* __restrict__ abuf0) {
  int idx = blockIdx.x * 256 + threadIdx.x;
  if (idx >= LLX * RBr * FFX) return;
  int f   = idx & (FFX - 1);
  int row = (idx >> 5) & (RBr - 1);
  int s   = idx / (RBr * FFX);
  int g = row >> 6, b = row & 63;
  int o = s - g;
  float v = (o >= 0 && o < OO) ? inp[((b * RR + g) * OO + o) * FFX + f] : 0.0f;
  abuf0[idx] = f2b(v);
}

__global__ __launch_bounds__(256) void k_zero(uint32_t* __restrict__ p, size_t nwords) {
  size_t i = (size_t)blockIdx.x * 256 + threadIdx.x;
  size_t stride = (size_t)gridDim.x * 256;
  for (; i < nwords; i += stride) p[i] = 0u;
}

// Per-component (24-block) step barrier. light: no fences (intra-XCD coherence
// via L2 + L1 invalidate). heavy: agent fences (placement-safe fallback).
__device__ __forceinline__ void step_barrier(uint32_t* barC, uint32_t target, bool light) {
  __syncthreads();
  if (threadIdx.x == 0) {
    if (!light) __threadfence();
    __hip_atomic_fetch_add(barC, 1u, __ATOMIC_RELAXED, __HIP_MEMORY_SCOPE_AGENT);
    while (__hip_atomic_load(barC, __ATOMIC_RELAXED, __HIP_MEMORY_SCOPE_AGENT) < target)
      __builtin_amdgcn_s_sleep(1);
    if (!light) __threadfence();
  }
  __syncthreads();
  if (light) asm volatile("buffer_inv" ::: "memory");
}

template <int KK>
__device__ __forceinline__ void stage_w(const float* __restrict__ Wsrc, int jblk,
                                        u16* __restrict__ Wl) {
  constexpr int SLOTS = KK / 8;
  constexpr int SLP = (KK == 512) ? 64 : 40;
  for (int e = threadIdx.x; e < 96 * SLOTS; e += 512) {
    int wr = e / SLOTS, sl = e - wr * SLOTS;
    int srow = (wr >> 4) * 128 + jblk * 16 + (wr & 15);
    const float* src = Wsrc + (size_t)srow * KK + sl * 8;
    short8 v;
#pragma unroll
    for (int x = 0; x < 8; ++x) v[x] = (short)f2b(src[x]);
    *(short8*)&Wl[(wr * SLP + (sl ^ (wr & 7))) * 8] = v;
  }
}

template <int KK>
__device__ __forceinline__ void persist_body(char* __restrict__ ws,
                                             const float* __restrict__ Bias_l,
                                             float* __restrict__ out,
                                             int layer, int jblk, int bblk, bool light,
                                             u16* __restrict__ Wl,
                                             float* __restrict__ hcl,
                                             uint32_t* __restrict__ barC) {
  constexpr int KA  = KK - 256;
  constexpr int NCH = KK / 32;
  constexpr int SLP = (KK == 512) ? 64 : 40;
  const int tid = threadIdx.x;
  const int lane = tid & 63, w = tid >> 6;
  const int fr = lane & 15, hi = lane >> 4, fx = fr & 7;

  // A fragment rows: rl -> (gg=rl>>3, bb=rl&7); row = (w*4+gg)*64 + bblk*8 + bb
  const int a0row = (w * 4 + (fr >> 3)) * 64 + bblk * 8 + (fr & 7);
  const int a1row = a0row + 128;
  const int a0hz = a0row * 256 + hi * 8;
  const int a1hz = a1row * 256 + hi * 8;
  const int a0ka = a0row * KA + hi * 8;
  const int a1ka = a1row * KA + hi * 8;
  const int j = jblk * 16 + fr;
  int wb[6];
#pragma unroll
  for (int m = 0; m < 6; ++m) wb[m] = (m * 16 + fr) * SLP * 8;
  float bia[6];
#pragma unroll
  for (int m = 0; m < 6; ++m) bia[m] = Bias_l[m * 128 + j];

  u16*   hz_base = (u16*)(ws + OFF_HZ) + (size_t)layer * 2 * RBr * 256;
  u16*   actv    = (u16*)(ws + OFF_ACTV);
  u16*   abuf0   = (u16*)(ws + OFF_ABUF0);
  float* hid_row = out + (size_t)RBr * LLX * 256;
  float* hid_col = hid_row + (size_t)BBX * NLAY * RR * HH;

  float hr_reg[2][4];
#pragma unroll
  for (int rf = 0; rf < 2; ++rf)
#pragma unroll
    for (int q = 0; q < 4; ++q) hr_reg[rf][q] = 0.0f;

  for (int t = 0; t < TSTEPS; ++t) {
    const int s = t - layer;
    if (s >= 0 && s < LLX) {
      const int sW = s & 1, sR = sW ^ 1;
      const u16* hzR = hz_base + (size_t)sR * RBr * 256;
      u16*       hzW = hz_base + (size_t)sW * RBr * 256;
      const u16* asrc;
      if constexpr (KK == 288) asrc = abuf0 + (size_t)s * RBr * FFX;
      else                     asrc = actv + (size_t)((layer - 1) * 2 + sW) * RBr * 256;
      u16* actvO = actv + (size_t)(layer * 2 + sW) * RBr * 256;
      const float* hcR = hcl + sR * 4352;
      float*       hcW = hcl + sW * 4352;

      // ---- preload ALL A fragments for this step (one latency exposure) ----
      short8 pa0[NCH], pa1[NCH];
#pragma unroll
      for (int kc = 0; kc < NCH; ++kc) {
        if (kc < 8) {
          pa0[kc] = *(const short8*)&hzR[a0hz + kc * 32];
          pa1[kc] = *(const short8*)&hzR[a1hz + kc * 32];
        } else if constexpr (KK == 512) {
          pa0[kc] = *(const short8*)&asrc[a0ka + (kc - 8) * 32];
          pa1[kc] = *(const short8*)&asrc[a1ka + (kc - 8) * 32];
        } else {
          pa0[kc] = *(const short8*)&asrc[a0ka];
          pa1[kc] = *(const short8*)&asrc[a1ka];
        }
      }

      f32x4 z4 = {0.f, 0.f, 0.f, 0.f};
      f32x4 acc[2][6];
#pragma unroll
      for (int rf = 0; rf < 2; ++rf)
#pragma unroll
        for (int m = 0; m < 6; ++m) acc[rf][m] = z4;

      __builtin_amdgcn_s_setprio(1);
#pragma unroll
      for (int kc = 0; kc < NCH; ++kc) {
#pragma unroll
        for (int m = 0; m < 6; ++m) {
          short8 bv = *(const short8*)&Wl[wb[m] + (((kc * 4 + hi) ^ fx) << 3)];
          acc[0][m] = __builtin_amdgcn_mfma_f32_16x16x32_bf16(pa0[kc], bv, acc[0][m], 0, 0, 0);
          acc[1][m] = __builtin_amdgcn_mfma_f32_16x16x32_bf16(pa1[kc], bv, acc[1][m], 0, 0, 0);
        }
      }
      __builtin_amdgcn_s_setprio(0);

      // ---- fused pointwise epilogue ----
#pragma unroll
      for (int rf = 0; rf < 2; ++rf) {
#pragma unroll
        for (int q = 0; q < 4; ++q) {
          const int g  = w * 4 + rf * 2 + (hi >> 1);
          const int lb = (hi & 1) * 4 + q;
          const int b  = bblk * 8 + lb;
          const int row = g * 64 + b;
          const int lrow = g * 8 + lb;
          const int gp = (g + 1) & (RR - 1);
          const int rp = gp * 64 + b;
          const int lrp = gp * 8 + lb;
          float msk = (g <= s && s < RR) ? 1.0f : 0.0f;
          float ur  = sigmoidf_(acc[rf][0][q] + msk * bia[0]);
          float orw = sigmoidf_(acc[rf][1][q] + msk * bia[1]);
          float uc  = sigmoidf_(acc[rf][2][q] + msk * bia[2]);
          float oc  = sigmoidf_(acc[rf][3][q] + msk * bia[3]);
          float ir  = tanhf_(acc[rf][4][q] + msk * bia[4]);
          float ic  = tanhf_(acc[rf][5][q] + msk * bia[5]);
          float hr_o = hr_reg[rf][q];
          float hc_o = hcR[lrow * 17 + fr];
          float hr_n = tanhf_((1.0f - ur) * hr_o + ur * ir) * orw;
          float hc_n = tanhf_((1.0f - uc) * hc_o + uc * ic) * oc;
          hr_reg[rf][q] = hr_n;
          hcW[lrp * 17 + fr] = hc_n;
          hzW[row * 256 + j] = f2b(hr_n);
          hzW[rp * 256 + HH + j] = f2b(hc_n);
          if (layer == 2) {
            out[((size_t)row * LLX + s) * 256 + j] = hr_n;
            out[((size_t)row * LLX + s) * 256 + HH + j] = hc_n;
          } else {
            actvO[row * 256 + j] = f2b(hr_n);
            actvO[row * 256 + HH + j] = f2b(hc_n);
          }
          if (s - g == OO - 1)
            hid_row[((size_t)(b * NLAY + layer) * RR + g) * HH + j] = hr_n;
          if (g == RR - 1 && s >= RR - 1)
            hid_col[((size_t)(b * NLAY + layer) * OO + (s - (RR - 1))) * HH + j] = hc_n;
        }
      }
    }
    step_barrier(barC, 24u * (uint32_t)(t + 1), light);
  }
}

__global__ __launch_bounds__(512) void k_persist(char* __restrict__ ws,
                                                 const float* __restrict__ Wf,
                                                 const float* __restrict__ Wo,
                                                 const float* __restrict__ Bias,
                                                 float* __restrict__ out) {
  __shared__ u16 Wl[49152];       // 96 KiB: W slice, XOR-swizzled
  __shared__ float hcl[8704];     // 34 KiB: hc state, dbuf, stride-17 (bank-spread)
  __shared__ uint32_t sh_light;
  const int bx = blockIdx.x;
  const int layer = bx >> 6, jblk = (bx >> 3) & 7, bblk = bx & 7;
  const int tid = threadIdx.x;

  if (layer == 0) stage_w<288>(Wf, jblk, Wl);
  else            stage_w<512>(Wo + (size_t)(layer - 1) * N6 * 512, jblk, Wl);
  for (int e = tid; e < 8704; e += 512) hcl[e] = 0.0f;

  // placement check: one-time global heavy barrier + per-component XCD match
  uint32_t xcc;
  asm volatile("s_getreg_b32 %0, hwreg(20, 0, 4)" : "=s"(xcc));
  uint32_t* barG  = (uint32_t*)(ws + OFF_BAR);
  uint32_t* barC  = (uint32_t*)(ws + OFF_BAR + 128 + (size_t)bblk * 128);
  uint32_t* table = (uint32_t*)(ws + OFF_BAR + 2048);
  __syncthreads();
  if (tid == 0) {
    __hip_atomic_store(&table[bx], xcc, __ATOMIC_RELAXED, __HIP_MEMORY_SCOPE_AGENT);
    __hip_atomic_fetch_add(barG, 1u, __ATOMIC_RELEASE, __HIP_MEMORY_SCOPE_AGENT);
    while (__hip_atomic_load(barG, __ATOMIC_ACQUIRE, __HIP_MEMORY_SCOPE_AGENT) < NBLOCKS)
      __builtin_amdgcn_s_sleep(1);
    uint32_t lt = 1u;
    for (int q2 = 0; q2 < 24; ++q2) {
      uint32_t v = __hip_atomic_load(&table[q2 * 8 + bblk], __ATOMIC_RELAXED,
                                     __HIP_MEMORY_SCOPE_AGENT);
      lt &= (v == xcc) ? 1u : 0u;
    }
    sh_light = lt;
  }
  __syncthreads();
  const bool light = (sh_light != 0u);

  const float* bias_l = Bias + layer * N6;
  if (layer == 0)
    persist_body<288>(ws, bias_l, out, 0, jblk, bblk, light, Wl, hcl, barC);
  else
    persist_body<512>(ws, bias_l, out, layer, jblk, bblk, light, Wl, hcl, barC);
}

extern "C" void kernel_launch(void* const* d_in, const int* in_sizes, int n_in,
                              void* d_out, int out_size, void* d_ws, size_t ws_size,
                              hipStream_t stream) {
  const float* inp  = (const float*)d_in[0];
  const float* Wf   = (const float*)d_in[1];
  const float* Wo   = (const float*)d_in[2];
  const float* Bias = (const float*)d_in[3];
  float* out = (float*)d_out;
  char* ws = (char*)d_ws;
  (void)in_sizes; (void)n_in; (void)out_size; (void)ws_size;

  k_prep_input<<<(LLX * RBr * FFX) / 256, 256, 0, stream>>>(inp, (u16*)(ws + OFF_ABUF0));
  k_zero<<<2048, 256, 0, stream>>>((uint32_t*)(ws + OFF_HZ), SZ_STATE / 4);
  k_persist<<<NBLOCKS, 512, 0, stream>>>(ws, Wf, Wo, Bias, out);
}

// Round 7
// 1183.655 us; speedup vs baseline: 1.3194x; 1.3194x over previous
//
#include <hip/hip_runtime.h>
#include <stdint.h>

#define HH   128
#define NLAY 3
#define RR   32
#define OO   48
#define BBX  64
#define FFX  32
#define LLX  (RR + OO - 1)    /* 79 */
#define RBr  (RR * BBX)       /* 2048 */
#define N6   (6 * HH)         /* 768 */
#define TSTEPS (LLX + NLAY - 1)  /* 81 */
#define NBLOCKS 192

typedef unsigned short u16;
typedef __attribute__((ext_vector_type(8))) short short8;
typedef __attribute__((ext_vector_type(4))) float f32x4;

// ---- workspace layout ----
#define OFF_ABUF0 ((size_t)0)
#define SZ_ABUF0  ((size_t)LLX * RBr * FFX * 2)
#define OFF_HZ    (OFF_ABUF0 + SZ_ABUF0)
#define SZ_HZ     ((size_t)NLAY * 2 * RBr * 256 * 2)   /* [l][slot][2048][256] bf16 */
#define OFF_BAR   (OFF_HZ + SZ_HZ)
#define SZ_BAR    ((size_t)4096)   /* barG @0, barC[b] @128+b*128, table @2048 */
#define SZ_STATE  (SZ_HZ + SZ_BAR)
#define OFF_ACTV  (OFF_BAR + SZ_BAR)
#define SZ_ACTV   ((size_t)2 * 2 * RBr * 256 * 2)

__device__ __forceinline__ u16 f2b(float x) {
  uint32_t u = __float_as_uint(x);
  return (u16)((u + 0x7FFFu + ((u >> 16) & 1u)) >> 16);
}
__device__ __forceinline__ float sigmoidf_(float x) {
  return 1.0f / (1.0f + __expf(-x));
}
__device__ __forceinline__ float tanhf_(float x) {
  float e = __expf(2.0f * x);
  return 1.0f - 2.0f / (e + 1.0f);
}

__global__ __launch_bounds__(256) void k_prep_input(const float* __restrict__ inp,
                                                    u16* __restrict__ abuf0) {
  int idx = blockIdx.x * 256 + threadIdx.x;
  if (idx >= LLX * RBr * FFX) return;
  int f   = idx & (FFX - 1);
  int row = (idx >> 5) & (RBr - 1);
  int s   = idx / (RBr * FFX);
  int g = row >> 6, b = row & 63;
  int o = s - g;
  float v = (o >= 0 && o < OO) ? inp[((b * RR + g) * OO + o) * FFX + f] : 0.0f;
  abuf0[idx] = f2b(v);
}

__global__ __launch_bounds__(256) void k_zero(uint32_t* __restrict__ p, size_t nwords) {
  size_t i = (size_t)blockIdx.x * 256 + threadIdx.x;
  size_t stride = (size_t)gridDim.x * 256;
  for (; i < nwords; i += stride) p[i] = 0u;
}

// Per-component (24-block) step barrier. light: no fences (intra-XCD coherence
// via L2 + L1 invalidate). heavy: agent fences (placement-safe fallback).
__device__ __forceinline__ void step_barrier(uint32_t* barC, uint32_t target, bool light) {
  __syncthreads();
  if (threadIdx.x == 0) {
    if (!light) __threadfence();
    __hip_atomic_fetch_add(barC, 1u, __ATOMIC_RELAXED, __HIP_MEMORY_SCOPE_AGENT);
    while (__hip_atomic_load(barC, __ATOMIC_RELAXED, __HIP_MEMORY_SCOPE_AGENT) < target)
      __builtin_amdgcn_s_sleep(1);
    if (!light) __threadfence();
  }
  __syncthreads();
  if (light) asm volatile("buffer_inv" ::: "memory");
}

// ---- stage W into LDS in MFMA fragment-consumption order ----
// chunk (kc, m, lane=(hi*16+fr)) at linear 16B index (kc*6+m)*64+lane holds
// W[m*128 + jblk*16 + fr][kc*32 + hi*8 .. +8] as bf16. A ds_read_b128 of
// fragment (kc,m) reads 64 consecutive 16B chunks -> conflict-free.
template <int KK>
__device__ __forceinline__ void stage_w(const float* __restrict__ Wsrc, int jblk,
                                        u16* __restrict__ Wl) {
  constexpr int NFRAG = (KK / 32) * 6;     // 54 or 96
  for (int e = threadIdx.x; e < NFRAG * 64; e += 512) {
    int kcm = e >> 6, ln = e & 63;
    int kc = kcm / 6, m = kcm - kc * 6;
    int fr2 = ln & 15, hi2 = ln >> 4;
    int srow = m * 128 + jblk * 16 + fr2;
    const float* src = Wsrc + (size_t)srow * KK + kc * 32 + hi2 * 8;
    short8 v;
#pragma unroll
    for (int x = 0; x < 8; ++x) v[x] = (short)f2b(src[x]);
    *(short8*)&Wl[(size_t)e * 8] = v;
  }
}

template <int KK>
__device__ __forceinline__ void persist_body(char* __restrict__ ws,
                                             const float* __restrict__ Bias_l,
                                             float* __restrict__ out,
                                             int layer, int jblk, int bblk, bool light,
                                             u16* __restrict__ Wl,
                                             float* __restrict__ hcl,
                                             uint32_t* __restrict__ barC) {
  constexpr int KA  = KK - 256;
  constexpr int NCH = KK / 32;
  const int tid = threadIdx.x;
  const int lane = tid & 63, w = tid >> 6;
  const int fr = lane & 15, hi = lane >> 4;

  // A fragment rows: rl -> (gg=rl>>3, bb=rl&7); row = (w*4+gg)*64 + bblk*8 + bb
  const int a0row = (w * 4 + (fr >> 3)) * 64 + bblk * 8 + (fr & 7);
  const int a1row = a0row + 128;
  const int a0hz = a0row * 256 + hi * 8;
  const int a1hz = a1row * 256 + hi * 8;
  const int a0ka = a0row * KA + hi * 8;
  const int a1ka = a1row * KA + hi * 8;
  const int j = jblk * 16 + fr;
  const u16* wfrag = &Wl[lane * 8];        // fragment base for this lane
  float bia[6];
#pragma unroll
  for (int m = 0; m < 6; ++m) bia[m] = Bias_l[m * 128 + j];

  u16*   hz_base = (u16*)(ws + OFF_HZ) + (size_t)layer * 2 * RBr * 256;
  u16*   actv    = (u16*)(ws + OFF_ACTV);
  u16*   abuf0   = (u16*)(ws + OFF_ABUF0);
  float* hid_row = out + (size_t)RBr * LLX * 256;
  float* hid_col = hid_row + (size_t)BBX * NLAY * RR * HH;

  float hr_reg[2][4];
#pragma unroll
  for (int rf = 0; rf < 2; ++rf)
#pragma unroll
    for (int q = 0; q < 4; ++q) hr_reg[rf][q] = 0.0f;

  for (int t = 0; t < TSTEPS; ++t) {
    const int s = t - layer;
    if (s >= 0 && s < LLX) {
      const int sW = s & 1, sR = sW ^ 1;
      const u16* hzR = hz_base + (size_t)sR * RBr * 256;
      u16*       hzW = hz_base + (size_t)sW * RBr * 256;
      const u16* asrc;
      if constexpr (KK == 288) asrc = abuf0 + (size_t)s * RBr * FFX;
      else                     asrc = actv + (size_t)((layer - 1) * 2 + sW) * RBr * 256;
      u16* actvO = actv + (size_t)(layer * 2 + sW) * RBr * 256;
      const float* hcR = hcl + sR * 4352;
      float*       hcW = hcl + sW * 4352;

      // ---- preload ALL A fragments (fits: VGPR cap raised to 256) ----
      short8 pa0[NCH], pa1[NCH];
#pragma unroll
      for (int kc = 0; kc < NCH; ++kc) {
        if (kc < 8) {
          pa0[kc] = *(const short8*)&hzR[a0hz + kc * 32];
          pa1[kc] = *(const short8*)&hzR[a1hz + kc * 32];
        } else if constexpr (KK == 512) {
          pa0[kc] = *(const short8*)&asrc[a0ka + (kc - 8) * 32];
          pa1[kc] = *(const short8*)&asrc[a1ka + (kc - 8) * 32];
        } else {
          pa0[kc] = *(const short8*)&asrc[a0ka];
          pa1[kc] = *(const short8*)&asrc[a1ka];
        }
      }

      f32x4 z4 = {0.f, 0.f, 0.f, 0.f};
      f32x4 acc[2][6];
#pragma unroll
      for (int rf = 0; rf < 2; ++rf)
#pragma unroll
        for (int m = 0; m < 6; ++m) acc[rf][m] = z4;

      __builtin_amdgcn_s_setprio(1);
#pragma unroll
      for (int kc = 0; kc < NCH; ++kc) {
#pragma unroll
        for (int m = 0; m < 6; ++m) {
          short8 bv = *(const short8*)&wfrag[(size_t)(kc * 6 + m) * 512];
          acc[0][m] = __builtin_amdgcn_mfma_f32_16x16x32_bf16(pa0[kc], bv, acc[0][m], 0, 0, 0);
          acc[1][m] = __builtin_amdgcn_mfma_f32_16x16x32_bf16(pa1[kc], bv, acc[1][m], 0, 0, 0);
        }
      }
      __builtin_amdgcn_s_setprio(0);

      // ---- fused pointwise epilogue ----
#pragma unroll
      for (int rf = 0; rf < 2; ++rf) {
#pragma unroll
        for (int q = 0; q < 4; ++q) {
          const int g  = w * 4 + rf * 2 + (hi >> 1);
          const int lb = (hi & 1) * 4 + q;
          const int b  = bblk * 8 + lb;
          const int row = g * 64 + b;
          const int lrow = g * 8 + lb;
          const int gp = (g + 1) & (RR - 1);
          const int rp = gp * 64 + b;
          const int lrp = gp * 8 + lb;
          float msk = (g <= s && s < RR) ? 1.0f : 0.0f;
          float ur  = sigmoidf_(acc[rf][0][q] + msk * bia[0]);
          float orw = sigmoidf_(acc[rf][1][q] + msk * bia[1]);
          float uc  = sigmoidf_(acc[rf][2][q] + msk * bia[2]);
          float oc  = sigmoidf_(acc[rf][3][q] + msk * bia[3]);
          float ir  = tanhf_(acc[rf][4][q] + msk * bia[4]);
          float ic  = tanhf_(acc[rf][5][q] + msk * bia[5]);
          float hr_o = hr_reg[rf][q];
          float hc_o = hcR[lrow * 17 + fr];
          float hr_n = tanhf_((1.0f - ur) * hr_o + ur * ir) * orw;
          float hc_n = tanhf_((1.0f - uc) * hc_o + uc * ic) * oc;
          hr_reg[rf][q] = hr_n;
          hcW[lrp * 17 + fr] = hc_n;
          hzW[row * 256 + j] = f2b(hr_n);
          hzW[rp * 256 + HH + j] = f2b(hc_n);
          if (layer == 2) {
            out[((size_t)row * LLX + s) * 256 + j] = hr_n;
            out[((size_t)row * LLX + s) * 256 + HH + j] = hc_n;
          } else {
            actvO[row * 256 + j] = f2b(hr_n);
            actvO[row * 256 + HH + j] = f2b(hc_n);
          }
          if (s - g == OO - 1)
            hid_row[((size_t)(b * NLAY + layer) * RR + g) * HH + j] = hr_n;
          if (g == RR - 1 && s >= RR - 1)
            hid_col[((size_t)(b * NLAY + layer) * OO + (s - (RR - 1))) * HH + j] = hc_n;
        }
      }
    }
    step_barrier(barC, 24u * (uint32_t)(t + 1), light);
  }
}

__global__ __launch_bounds__(512, 2) void k_persist(char* __restrict__ ws,
                                                    const float* __restrict__ Wf,
                                                    const float* __restrict__ Wo,
                                                    const float* __restrict__ Bias,
                                                    float* __restrict__ out) {
  __shared__ u16 Wl[49152];       // 96 KiB: W slice, fragment-contiguous
  __shared__ float hcl[8704];     // 34 KiB: hc state, dbuf, stride-17
  __shared__ uint32_t sh_light;
  const int bx = blockIdx.x;
  const int layer = bx >> 6, jblk = (bx >> 3) & 7, bblk = bx & 7;
  const int tid = threadIdx.x;

  if (layer == 0) stage_w<288>(Wf, jblk, Wl);
  else            stage_w<512>(Wo + (size_t)(layer - 1) * N6 * 512, jblk, Wl);
  for (int e = tid; e < 8704; e += 512) hcl[e] = 0.0f;

  // placement check: one-time global heavy barrier + per-component XCD match
  uint32_t xcc;
  asm volatile("s_getreg_b32 %0, hwreg(20, 0, 4)" : "=s"(xcc));
  uint32_t* barG  = (uint32_t*)(ws + OFF_BAR);
  uint32_t* barC  = (uint32_t*)(ws + OFF_BAR + 128 + (size_t)bblk * 128);
  uint32_t* table = (uint32_t*)(ws + OFF_BAR + 2048);
  __syncthreads();
  if (tid == 0) {
    __hip_atomic_store(&table[bx], xcc, __ATOMIC_RELAXED, __HIP_MEMORY_SCOPE_AGENT);
    __hip_atomic_fetch_add(barG, 1u, __ATOMIC_RELEASE, __HIP_MEMORY_SCOPE_AGENT);
    while (__hip_atomic_load(barG, __ATOMIC_ACQUIRE, __HIP_MEMORY_SCOPE_AGENT) < NBLOCKS)
      __builtin_amdgcn_s_sleep(1);
    uint32_t lt = 1u;
    for (int q2 = 0; q2 < 24; ++q2) {
      uint32_t v = __hip_atomic_load(&table[q2 * 8 + bblk], __ATOMIC_RELAXED,
                                     __HIP_MEMORY_SCOPE_AGENT);
      lt &= (v == xcc) ? 1u : 0u;
    }
    sh_light = lt;
  }
  __syncthreads();
  const bool light = (sh_light != 0u);

  const float* bias_l = Bias + layer * N6;
  if (layer == 0)
    persist_body<288>(ws, bias_l, out, 0, jblk, bblk, light, Wl, hcl, barC);
  else
    persist_body<512>(ws, bias_l, out, layer, jblk, bblk, light, Wl, hcl, barC);
}

extern "C" void kernel_launch(void* const* d_in, const int* in_sizes, int n_in,
                              void* d_out, int out_size, void* d_ws, size_t ws_size,
                              hipStream_t stream) {
  const float* inp  = (const float*)d_in[0];
  const float* Wf   = (const float*)d_in[1];
  const float* Wo   = (const float*)d_in[2];
  const float* Bias = (const float*)d_in[3];
  float* out = (float*)d_out;
  char* ws = (char*)d_ws;
  (void)in_sizes; (void)n_in; (void)out_size; (void)ws_size;

  k_prep_input<<<(LLX * RBr * FFX) / 256, 256, 0, stream>>>(inp, (u16*)(ws + OFF_ABUF0));
  k_zero<<<2048, 256, 0, stream>>>((uint32_t*)(ws + OFF_HZ), SZ_STATE / 4);
  k_persist<<<NBLOCKS, 512, 0, stream>>>(ws, Wf, Wo, Bias, out);
}

// Round 8
// 918.920 us; speedup vs baseline: 1.6995x; 1.2881x over previous
//
#include <hip/hip_runtime.h>
#include <stdint.h>

#define HH   128
#define NLAY 3
#define RR   32
#define OO   48
#define BBX  64
#define FFX  32
#define LLX  (RR + OO - 1)    /* 79 */
#define RBr  (RR * BBX)       /* 2048 */
#define N6   (6 * HH)         /* 768 */
#define TSTEPS (LLX + NLAY - 1)  /* 81 */
#define NBLOCKS 192

typedef unsigned short u16;
typedef __attribute__((ext_vector_type(8))) short short8;
typedef __attribute__((ext_vector_type(4))) float f32x4;

// ---- workspace layout ----
#define OFF_ABUF0 ((size_t)0)
#define SZ_ABUF0  ((size_t)LLX * RBr * FFX * 2)
#define OFF_HZ    (OFF_ABUF0 + SZ_ABUF0)
#define SZ_HZ     ((size_t)NLAY * 2 * RBr * 256 * 2)   /* [l][slot][2048][256] bf16 */
#define OFF_BAR   (OFF_HZ + SZ_HZ)
#define SZ_BAR    ((size_t)4096)   /* barG @0, barC[b] @128+b*128, table @2048 */
#define SZ_STATE  (SZ_HZ + SZ_BAR)

__device__ __forceinline__ u16 f2b(float x) {
  uint32_t u = __float_as_uint(x);
  return (u16)((u + 0x7FFFu + ((u >> 16) & 1u)) >> 16);
}
__device__ __forceinline__ float rcp_(float x) { return __builtin_amdgcn_rcpf(x); }
__device__ __forceinline__ float sigmoidf_(float x) {
  return rcp_(1.0f + __expf(-x));
}
__device__ __forceinline__ float tanhf_(float x) {
  return 1.0f - 2.0f * rcp_(__expf(2.0f * x) + 1.0f);
}

__global__ __launch_bounds__(256) void k_prep_input(const float* __restrict__ inp,
                                                    u16* __restrict__ abuf0) {
  int idx = blockIdx.x * 256 + threadIdx.x;
  if (idx >= LLX * RBr * FFX) return;
  int f   = idx & (FFX - 1);
  int row = (idx >> 5) & (RBr - 1);
  int s   = idx / (RBr * FFX);
  int g = row >> 6, b = row & 63;
  int o = s - g;
  float v = (o >= 0 && o < OO) ? inp[((b * RR + g) * OO + o) * FFX + f] : 0.0f;
  abuf0[idx] = f2b(v);
}

__global__ __launch_bounds__(256) void k_zero(uint32_t* __restrict__ p, size_t nwords) {
  size_t i = (size_t)blockIdx.x * 256 + threadIdx.x;
  size_t stride = (size_t)gridDim.x * 256;
  for (; i < nwords; i += stride) p[i] = 0u;
}

// Per-component (24-block) step barrier. light: no fences (same-XCD L2 is the
// coherence point; L1 flushed via buffer_inv). heavy: agent fences (fallback).
__device__ __forceinline__ void step_barrier(uint32_t* barC, uint32_t target, bool light) {
  __syncthreads();
  if (threadIdx.x == 0) {
    if (!light) __threadfence();
    __hip_atomic_fetch_add(barC, 1u, __ATOMIC_RELAXED, __HIP_MEMORY_SCOPE_AGENT);
    while (__hip_atomic_load(barC, __ATOMIC_RELAXED, __HIP_MEMORY_SCOPE_AGENT) < target)
      __builtin_amdgcn_s_sleep(1);
    if (!light) __threadfence();
  }
  __syncthreads();
  if (light) asm volatile("buffer_inv" ::: "memory");
}

// ---- stage W into LDS in MFMA fragment-consumption order (conflict-free) ----
template <int KK>
__device__ __forceinline__ void stage_w(const float* __restrict__ Wsrc, int jblk,
                                        u16* __restrict__ Wl) {
  constexpr int NFRAG = (KK / 32) * 6;     // 54 or 96
  for (int e = threadIdx.x; e < NFRAG * 64; e += 512) {
    int kcm = e >> 6, ln = e & 63;
    int kc = kcm / 6, m = kcm - kc * 6;
    int fr2 = ln & 15, hi2 = ln >> 4;
    int srow = m * 128 + jblk * 16 + fr2;
    const float* src = Wsrc + (size_t)srow * KK + kc * 32 + hi2 * 8;
    short8 v;
#pragma unroll
    for (int x = 0; x < 8; ++x) v[x] = (short)f2b(src[x]);
    *(short8*)&Wl[(size_t)e * 8] = v;
  }
}

template <int KK>
__device__ __forceinline__ void persist_body(char* __restrict__ ws,
                                             const float* __restrict__ Bias_l,
                                             float* __restrict__ out,
                                             int layer, int jblk, int bblk, bool light,
                                             u16* __restrict__ Wl,
                                             float* __restrict__ hcl,
                                             uint32_t* __restrict__ barC) {
  constexpr int NCH = KK / 32;
  const int tid = threadIdx.x;
  const int lane = tid & 63, w = tid >> 6;
  const int fr = lane & 15, hi = lane >> 4;

  // A fragment rows: fr -> (gg=fr>>3, bb=fr&7); row = (w*4+gg)*64 + bblk*8 + bb
  const int g0   = w * 4 + (fr >> 3);
  const int bcol = bblk * 8 + (fr & 7);
  const int a0row = g0 * 64 + bcol;
  const int a1row = a0row + 128;               // group g0+2
  const int a0rp  = (((g0 + 1) & 31)) * 64 + bcol;  // rolled row (hc source, prev layer)
  const int a1rp  = (((g0 + 3) & 31)) * 64 + bcol;
  const int j = jblk * 16 + fr;
  const u16* wfrag = &Wl[lane * 8];
  float bia[6];
#pragma unroll
  for (int m = 0; m < 6; ++m) bia[m] = Bias_l[m * 128 + j];

  u16*   hz_base  = (u16*)(ws + OFF_HZ) + (size_t)layer * 2 * RBr * 256;
  u16*   hzp_base = (u16*)(ws + OFF_HZ) + (size_t)(layer - 1) * 2 * RBr * 256;
  u16*   abuf0    = (u16*)(ws + OFF_ABUF0);
  float* hid_row  = out + (size_t)RBr * LLX * 256;
  float* hid_col  = hid_row + (size_t)BBX * NLAY * RR * HH;

  float hr_reg[2][4];
#pragma unroll
  for (int rf = 0; rf < 2; ++rf)
#pragma unroll
    for (int q = 0; q < 4; ++q) hr_reg[rf][q] = 0.0f;

  for (int t = 0; t < TSTEPS; ++t) {
    const int s = t - layer;
    if (s >= 0 && s < LLX) {
      const int sW = s & 1, sR = sW ^ 1;
      const u16* hzR = hz_base + (size_t)sR * RBr * 256;
      u16*       hzW = hz_base + (size_t)sW * RBr * 256;
      const u16* hzP = hzp_base + (size_t)sW * RBr * 256;  // prev layer, slice s (t-1)
      const u16* ab_s = abuf0 + (size_t)s * RBr * FFX;
      const float* hcR = hcl + sR * 4352;
      float*       hcW = hcl + sW * 4352;

      f32x4 z4 = {0.f, 0.f, 0.f, 0.f};
      f32x4 acc[2][6];
#pragma unroll
      for (int rf = 0; rf < 2; ++rf)
#pragma unroll
        for (int m = 0; m < 6; ++m) acc[rf][m] = z4;

      __builtin_amdgcn_s_setprio(1);
#pragma unroll
      for (int kc = 0; kc < NCH; ++kc) {
        short8 a0, a1;
        if (kc < 8) {                       // own hz: [hr | rolled hc]
          a0 = *(const short8*)&hzR[a0row * 256 + kc * 32 + hi * 8];
          a1 = *(const short8*)&hzR[a1row * 256 + kc * 32 + hi * 8];
        } else if constexpr (KK == 288) {   // layer 0: wavefront input
          a0 = *(const short8*)&ab_s[a0row * FFX + hi * 8];
          a1 = *(const short8*)&ab_s[a1row * FFX + hi * 8];
        } else if (kc < 12) {               // prev layer hr (unrolled rows)
          const int c = (kc - 8) * 32 + hi * 8;
          a0 = *(const short8*)&hzP[a0row * 256 + c];
          a1 = *(const short8*)&hzP[a1row * 256 + c];
        } else {                            // prev layer hc (inverse-roll rows)
          const int c = 128 + (kc - 12) * 32 + hi * 8;
          a0 = *(const short8*)&hzP[a0rp * 256 + c];
          a1 = *(const short8*)&hzP[a1rp * 256 + c];
        }
#pragma unroll
        for (int m = 0; m < 6; ++m) {
          short8 bv = *(const short8*)&wfrag[(size_t)(kc * 6 + m) * 512];
          acc[0][m] = __builtin_amdgcn_mfma_f32_16x16x32_bf16(a0, bv, acc[0][m], 0, 0, 0);
          acc[1][m] = __builtin_amdgcn_mfma_f32_16x16x32_bf16(a1, bv, acc[1][m], 0, 0, 0);
        }
      }
      __builtin_amdgcn_s_setprio(0);

      // ---- fused pointwise epilogue ----
#pragma unroll
      for (int rf = 0; rf < 2; ++rf) {
        const int g = w * 4 + rf * 2 + (hi >> 1);
        const int gp = (g + 1) & (RR - 1);
        const float msk = (g <= s && s < RR) ? 1.0f : 0.0f;
        float mb[6];
#pragma unroll
        for (int m = 0; m < 6; ++m) mb[m] = msk * bia[m];
#pragma unroll
        for (int q = 0; q < 4; ++q) {
          const int lb = (hi & 1) * 4 + q;
          const int b  = bblk * 8 + lb;
          const int row = g * 64 + b;
          const int lrow = g * 8 + lb;
          const int rp = gp * 64 + b;
          const int lrp = gp * 8 + lb;
          float ur  = sigmoidf_(acc[rf][0][q] + mb[0]);
          float orw = sigmoidf_(acc[rf][1][q] + mb[1]);
          float uc  = sigmoidf_(acc[rf][2][q] + mb[2]);
          float oc  = sigmoidf_(acc[rf][3][q] + mb[3]);
          float ir  = tanhf_(acc[rf][4][q] + mb[4]);
          float ic  = tanhf_(acc[rf][5][q] + mb[5]);
          float hr_o = hr_reg[rf][q];
          float hc_o = hcR[lrow * 17 + fr];
          float hr_n = tanhf_((1.0f - ur) * hr_o + ur * ir) * orw;
          float hc_n = tanhf_((1.0f - uc) * hc_o + uc * ic) * oc;
          hr_reg[rf][q] = hr_n;
          hcW[lrp * 17 + fr] = hc_n;
          hzW[row * 256 + j] = f2b(hr_n);
          hzW[rp * 256 + HH + j] = f2b(hc_n);
          if (layer == 2) {
            out[((size_t)row * LLX + s) * 256 + j] = hr_n;
            out[((size_t)row * LLX + s) * 256 + HH + j] = hc_n;
          }
          if (s - g == OO - 1)
            hid_row[((size_t)(b * NLAY + layer) * RR + g) * HH + j] = hr_n;
          if (g == RR - 1 && s >= RR - 1)
            hid_col[((size_t)(b * NLAY + layer) * OO + (s - (RR - 1))) * HH + j] = hc_n;
        }
      }
    }
    step_barrier(barC, 24u * (uint32_t)(t + 1), light);
  }
}

__global__ __launch_bounds__(512) void k_persist(char* __restrict__ ws,
                                                 const float* __restrict__ Wf,
                                                 const float* __restrict__ Wo,
                                                 const float* __restrict__ Bias,
                                                 float* __restrict__ out) {
  __shared__ u16 Wl[49152];       // 96 KiB: W slice, fragment-contiguous
  __shared__ float hcl[8704];     // 34 KiB: hc state, dbuf, stride-17
  __shared__ uint32_t sh_light;
  const int bx = blockIdx.x;
  const int layer = bx >> 6, jblk = (bx >> 3) & 7, bblk = bx & 7;
  const int tid = threadIdx.x;

  if (layer == 0) stage_w<288>(Wf, jblk, Wl);
  else            stage_w<512>(Wo + (size_t)(layer - 1) * N6 * 512, jblk, Wl);
  for (int e = tid; e < 8704; e += 512) hcl[e] = 0.0f;

  // placement check: one-time global heavy barrier + per-component XCD match
  uint32_t xcc;
  asm volatile("s_getreg_b32 %0, hwreg(20, 0, 4)" : "=s"(xcc));
  uint32_t* barG  = (uint32_t*)(ws + OFF_BAR);
  uint32_t* barC  = (uint32_t*)(ws + OFF_BAR + 128 + (size_t)bblk * 128);
  uint32_t* table = (uint32_t*)(ws + OFF_BAR + 2048);
  __syncthreads();
  if (tid == 0) {
    __hip_atomic_store(&table[bx], xcc, __ATOMIC_RELAXED, __HIP_MEMORY_SCOPE_AGENT);
    __hip_atomic_fetch_add(barG, 1u, __ATOMIC_RELEASE, __HIP_MEMORY_SCOPE_AGENT);
    while (__hip_atomic_load(barG, __ATOMIC_ACQUIRE, __HIP_MEMORY_SCOPE_AGENT) < NBLOCKS)
      __builtin_amdgcn_s_sleep(1);
    uint32_t lt = 1u;
    for (int q2 = 0; q2 < 24; ++q2) {
      uint32_t v = __hip_atomic_load(&table[q2 * 8 + bblk], __ATOMIC_RELAXED,
                                     __HIP_MEMORY_SCOPE_AGENT);
      lt &= (v == xcc) ? 1u : 0u;
    }
    sh_light = lt;
  }
  __syncthreads();
  const bool light = (sh_light != 0u);

  const float* bias_l = Bias + layer * N6;
  if (layer == 0)
    persist_body<288>(ws, bias_l, out, 0, jblk, bblk, light, Wl, hcl, barC);
  else
    persist_body<512>(ws, bias_l, out, layer, jblk, bblk, light, Wl, hcl, barC);
}

extern "C" void kernel_launch(void* const* d_in, const int* in_sizes, int n_in,
                              void* d_out, int out_size, void* d_ws, size_t ws_size,
                              hipStream_t stream) {
  const float* inp  = (const float*)d_in[0];
  const float* Wf   = (const float*)d_in[1];
  const float* Wo   = (const float*)d_in[2];
  const float* Bias = (const float*)d_in[3];
  float* out = (float*)d_out;
  char* ws = (char*)d_ws;
  (void)in_sizes; (void)n_in; (void)out_size; (void)ws_size;

  k_prep_input<<<(LLX * RBr * FFX) / 256, 256, 0, stream>>>(inp, (u16*)(ws + OFF_ABUF0));
  k_zero<<<2048, 256, 0, stream>>>((uint32_t*)(ws + OFF_HZ), SZ_STATE / 4);
  k_persist<<<NBLOCKS, 512, 0, stream>>>(ws, Wf, Wo, Bias, out);
}

// Round 10
// 827.178 us; speedup vs baseline: 1.8880x; 1.1109x over previous
//
#include <hip/hip_runtime.h>
#include <stdint.h>

#define HH   128
#define NLAY 3
#define RR   32
#define OO   48
#define BBX  64
#define FFX  32
#define LLX  (RR + OO - 1)    /* 79 */
#define RBr  (RR * BBX)       /* 2048 */
#define N6   (6 * HH)         /* 768 */
#define TSTEPS (LLX + NLAY - 1)  /* 81 */
#define NBLOCKS 192

typedef unsigned short u16;
typedef __attribute__((ext_vector_type(8))) short short8;
typedef __attribute__((ext_vector_type(4))) float f32x4;

// ---- workspace layout ----
#define OFF_ABUF0 ((size_t)0)
#define SZ_ABUF0  ((size_t)LLX * RBr * FFX * 2)
#define OFF_HZ    (OFF_ABUF0 + SZ_ABUF0)
#define SZ_HZ     ((size_t)NLAY * 2 * RBr * 256 * 2)   /* [l][slot][2048][256] bf16 */
#define OFF_BAR   (OFF_HZ + SZ_HZ)
#define SZ_BAR    ((size_t)4096)   /* barG @0, barC[b] @128+b*128, table @2048 */
#define SZ_STATE  (SZ_HZ + SZ_BAR)

__device__ __forceinline__ u16 f2b(float x) {
  uint32_t u = __float_as_uint(x);
  return (u16)((u + 0x7FFFu + ((u >> 16) & 1u)) >> 16);
}
__device__ __forceinline__ float rcp_(float x) { return __builtin_amdgcn_rcpf(x); }
__device__ __forceinline__ float sigmoidf_(float x) {
  return rcp_(1.0f + __expf(-x));
}
__device__ __forceinline__ float tanhf_(float x) {
  return 1.0f - 2.0f * rcp_(__expf(2.0f * x) + 1.0f);
}

__global__ __launch_bounds__(256) void k_prep_input(const float* __restrict__ inp,
                                                    u16* __restrict__ abuf0) {
  int idx = blockIdx.x * 256 + threadIdx.x;
  if (idx >= LLX * RBr * FFX) return;
  int f   = idx & (FFX - 1);
  int row = (idx >> 5) & (RBr - 1);
  int s   = idx / (RBr * FFX);
  int g = row >> 6, b = row & 63;
  int o = s - g;
  float v = (o >= 0 && o < OO) ? inp[((b * RR + g) * OO + o) * FFX + f] : 0.0f;
  abuf0[idx] = f2b(v);
}

__global__ __launch_bounds__(256) void k_zero(uint32_t* __restrict__ p, size_t nwords) {
  size_t i = (size_t)blockIdx.x * 256 + threadIdx.x;
  size_t stride = (size_t)gridDim.x * 256;
  for (; i < nwords; i += stride) p[i] = 0u;
}

// Per-component (24-block) step barrier. light: no fences (same-XCD L2 is the
// coherence point; L1 flushed via buffer_inv). heavy: agent fences (fallback).
__device__ __forceinline__ void step_barrier(uint32_t* barC, uint32_t target, bool light) {
  __syncthreads();
  if (threadIdx.x == 0) {
    if (!light) __threadfence();
    __hip_atomic_fetch_add(barC, 1u, __ATOMIC_RELAXED, __HIP_MEMORY_SCOPE_AGENT);
    while (__hip_atomic_load(barC, __ATOMIC_RELAXED, __HIP_MEMORY_SCOPE_AGENT) < target)
      __builtin_amdgcn_s_sleep(1);
    if (!light) __threadfence();
  }
  __syncthreads();
  if (light) asm volatile("buffer_inv" ::: "memory");
}

// ---- stage W into LDS in MFMA fragment-consumption order (conflict-free) ----
template <int KK>
__device__ __forceinline__ void stage_w(const float* __restrict__ Wsrc, int jblk,
                                        u16* __restrict__ Wl) {
  constexpr int NFRAG = (KK / 32) * 6;     // 54 or 96
  for (int e = threadIdx.x; e < NFRAG * 64; e += 512) {
    int kcm = e >> 6, ln = e & 63;
    int kc = kcm / 6, m = kcm - kc * 6;
    int fr2 = ln & 15, hi2 = ln >> 4;
    int srow = m * 128 + jblk * 16 + fr2;
    const float* src = Wsrc + (size_t)srow * KK + kc * 32 + hi2 * 8;
    short8 v;
#pragma unroll
    for (int x = 0; x < 8; ++x) v[x] = (short)f2b(src[x]);
    *(short8*)&Wl[(size_t)e * 8] = v;
  }
}

template <int KK>
__device__ __forceinline__ void persist_body(char* __restrict__ ws,
                                             const float* __restrict__ Bias_l,
                                             float* __restrict__ out,
                                             int layer, int jblk, int bblk, bool light,
                                             u16* __restrict__ Wl,
                                             float* __restrict__ hcl,
                                             uint32_t* __restrict__ barC) {
  constexpr int NCH = KK / 32;
  const int tid = threadIdx.x;
  const int lane = tid & 63, w = tid >> 6;
  const int fr = lane & 15, hi = lane >> 4;

  // phase p covers groups {4w+2p, 4w+2p+1}; fragment rows per phase:
  const int g0   = w * 4 + (fr >> 3);
  const int bcol = bblk * 8 + (fr & 7);
  const int arow[2] = { g0 * 64 + bcol, (g0 + 2) * 64 + bcol };
  const int arp[2]  = { ((g0 + 1) & 31) * 64 + bcol, ((g0 + 3) & 31) * 64 + bcol };
  const int j = jblk * 16 + fr;
  const u16* wfrag = &Wl[lane * 8];
  float bia[6];
#pragma unroll
  for (int m = 0; m < 6; ++m) bia[m] = Bias_l[m * 128 + j];

  u16*   hz_base  = (u16*)(ws + OFF_HZ) + (size_t)layer * 2 * RBr * 256;
  u16*   hzp_base = (u16*)(ws + OFF_HZ) + (size_t)(layer - 1) * 2 * RBr * 256;
  u16*   abuf0    = (u16*)(ws + OFF_ABUF0);
  float* hid_row  = out + (size_t)RBr * LLX * 256;
  float* hid_col  = hid_row + (size_t)BBX * NLAY * RR * HH;

  float hr_reg[2][4];
#pragma unroll
  for (int p = 0; p < 2; ++p)
#pragma unroll
    for (int q = 0; q < 4; ++q) hr_reg[p][q] = 0.0f;

  for (int t = 0; t < TSTEPS; ++t) {
    const int s = t - layer;
    if (s >= 0 && s < LLX) {
      const int sW = s & 1, sR = sW ^ 1;
      const u16* hzR = hz_base + (size_t)sR * RBr * 256;
      u16*       hzW = hz_base + (size_t)sW * RBr * 256;
      const u16* hzP = hzp_base + (size_t)sW * RBr * 256;  // prev layer, slice s
      const u16* ab_s = abuf0 + (size_t)s * RBr * FFX;
      const float* hcR = hcl + sR * 4352;
      float*       hcW = hcl + sW * 4352;

#pragma unroll
      for (int p = 0; p < 2; ++p) {
        if (w * 4 + 2 * p <= s) {
          // ---------------- active phase: GEMM + full epilogue ----------------
          auto LDK = [&](int kc) -> short8 {
            if (kc < 8)
              return *(const short8*)&hzR[arow[p] * 256 + kc * 32 + hi * 8];
            if constexpr (KK == 288) {
              return *(const short8*)&ab_s[arow[p] * FFX + hi * 8];
            } else {
              if (kc < 12)
                return *(const short8*)&hzP[arow[p] * 256 + (kc - 8) * 32 + hi * 8];
              return *(const short8*)&hzP[arp[p] * 256 + 128 + (kc - 12) * 32 + hi * 8];
            }
          };

          f32x4 z4 = {0.f, 0.f, 0.f, 0.f};
          f32x4 acc[6];
#pragma unroll
          for (int m = 0; m < 6; ++m) acc[m] = z4;

          short8 ring[3];
          ring[0] = LDK(0);
          ring[1] = LDK(1);
          ring[2] = LDK(2);
          __builtin_amdgcn_s_setprio(1);
#pragma unroll
          for (int kc = 0; kc < NCH; ++kc) {
            short8 a = ring[kc % 3];
            if (kc + 3 < NCH) ring[kc % 3] = LDK(kc + 3);
#pragma unroll
            for (int m = 0; m < 6; ++m) {
              short8 bv = *(const short8*)&wfrag[(size_t)(kc * 6 + m) * 512];
              acc[m] = __builtin_amdgcn_mfma_f32_16x16x32_bf16(a, bv, acc[m], 0, 0, 0);
            }
          }
          __builtin_amdgcn_s_setprio(0);

          const int g = w * 4 + 2 * p + (hi >> 1);
          const int gp = (g + 1) & (RR - 1);
          const float msk = (g <= s && s < RR) ? 1.0f : 0.0f;
          float mb[6];
#pragma unroll
          for (int m = 0; m < 6; ++m) mb[m] = msk * bia[m];
#pragma unroll
          for (int q = 0; q < 4; ++q) {
            const int lb = (hi & 1) * 4 + q;
            const int b  = bblk * 8 + lb;
            const int row = g * 64 + b;
            const int lrow = g * 8 + lb;
            const int rp = gp * 64 + b;
            const int lrp = gp * 8 + lb;
            float ur  = sigmoidf_(acc[0][q] + mb[0]);
            float orw = sigmoidf_(acc[1][q] + mb[1]);
            float uc  = sigmoidf_(acc[2][q] + mb[2]);
            float oc  = sigmoidf_(acc[3][q] + mb[3]);
            float ir  = tanhf_(acc[4][q] + mb[4]);
            float ic  = tanhf_(acc[5][q] + mb[5]);
            float hr_o = hr_reg[p][q];
            float hc_o = hcR[lrow * 17 + fr];
            float hr_n = tanhf_((1.0f - ur) * hr_o + ur * ir) * orw;
            float hc_n = tanhf_((1.0f - uc) * hc_o + uc * ic) * oc;
            hr_reg[p][q] = hr_n;
            hcW[lrp * 17 + fr] = hc_n;
            hzW[row * 256 + j] = f2b(hr_n);
            hzW[rp * 256 + HH + j] = f2b(hc_n);
            if (layer == 2) {
              out[((size_t)row * LLX + s) * 256 + j] = hr_n;
              out[((size_t)row * LLX + s) * 256 + HH + j] = hc_n;
            }
            if (s - g == OO - 1)
              hid_row[((size_t)(b * NLAY + layer) * RR + g) * HH + j] = hr_n;
            if (g == RR - 1 && s >= RR - 1)
              hid_col[((size_t)(b * NLAY + layer) * OO + (s - (RR - 1))) * HH + j] = hc_n;
          }
        } else {
          // -------- inactive phase: outputs are exactly zero; store them --------
          // (restores round-8 write semantics bit-exactly; no GEMM/exp needed;
          //  hid_row/hid_col conditions both imply g <= s -> never hit here)
          const int g = w * 4 + 2 * p + (hi >> 1);
          const int gp = (g + 1) & (RR - 1);
#pragma unroll
          for (int q = 0; q < 4; ++q) {
            const int lb = (hi & 1) * 4 + q;
            const int b  = bblk * 8 + lb;
            const int row = g * 64 + b;
            const int rp = gp * 64 + b;
            const int lrp = gp * 8 + lb;
            hcW[lrp * 17 + fr] = 0.0f;
            hzW[row * 256 + j] = 0;
            hzW[rp * 256 + HH + j] = 0;
            if (layer == 2) {
              out[((size_t)row * LLX + s) * 256 + j] = 0.0f;
              out[((size_t)row * LLX + s) * 256 + HH + j] = 0.0f;
            }
          }
        }
      }
    }
    step_barrier(barC, 24u * (uint32_t)(t + 1), light);
  }
}

__global__ __launch_bounds__(512) void k_persist(char* __restrict__ ws,
                                                 const float* __restrict__ Wf,
                                                 const float* __restrict__ Wo,
                                                 const float* __restrict__ Bias,
                                                 float* __restrict__ out) {
  __shared__ u16 Wl[49152];       // 96 KiB: W slice, fragment-contiguous
  __shared__ float hcl[8704];     // 34 KiB: hc state, dbuf, stride-17
  __shared__ uint32_t sh_light;
  const int bx = blockIdx.x;
  const int layer = bx >> 6, jblk = (bx >> 3) & 7, bblk = bx & 7;
  const int tid = threadIdx.x;

  if (layer == 0) stage_w<288>(Wf, jblk, Wl);
  else            stage_w<512>(Wo + (size_t)(layer - 1) * N6 * 512, jblk, Wl);
  for (int e = tid; e < 8704; e += 512) hcl[e] = 0.0f;

  // placement check: one-time global heavy barrier + per-component XCD match
  uint32_t xcc;
  asm volatile("s_getreg_b32 %0, hwreg(20, 0, 4)" : "=s"(xcc));
  uint32_t* barG  = (uint32_t*)(ws + OFF_BAR);
  uint32_t* barC  = (uint32_t*)(ws + OFF_BAR + 128 + (size_t)bblk * 128);
  uint32_t* table = (uint32_t*)(ws + OFF_BAR + 2048);
  __syncthreads();
  if (tid == 0) {
    __hip_atomic_store(&table[bx], xcc, __ATOMIC_RELAXED, __HIP_MEMORY_SCOPE_AGENT);
    __hip_atomic_fetch_add(barG, 1u, __ATOMIC_RELEASE, __HIP_MEMORY_SCOPE_AGENT);
    while (__hip_atomic_load(barG, __ATOMIC_ACQUIRE, __HIP_MEMORY_SCOPE_AGENT) < NBLOCKS)
      __builtin_amdgcn_s_sleep(1);
    uint32_t lt = 1u;
    for (int q2 = 0; q2 < 24; ++q2) {
      uint32_t v = __hip_atomic_load(&table[q2 * 8 + bblk], __ATOMIC_RELAXED,
                                     __HIP_MEMORY_SCOPE_AGENT);
      lt &= (v == xcc) ? 1u : 0u;
    }
    sh_light = lt;
  }
  __syncthreads();
  const bool light = (sh_light != 0u);

  const float* bias_l = Bias + layer * N6;
  if (layer == 0)
    persist_body<288>(ws, bias_l, out, 0, jblk, bblk, light, Wl, hcl, barC);
  else
    persist_body<512>(ws, bias_l, out, layer, jblk, bblk, light, Wl, hcl, barC);
}

extern "C" void kernel_launch(void* const* d_in, const int* in_sizes, int n_in,
                              void* d_out, int out_size, void* d_ws, size_t ws_size,
                              hipStream_t stream) {
  const float* inp  = (const float*)d_in[0];
  const float* Wf   = (const float*)d_in[1];
  const float* Wo   = (const float*)d_in[2];
  const float* Bias = (const float*)d_in[3];
  float* out = (float*)d_out;
  char* ws = (char*)d_ws;
  (void)in_sizes; (void)n_in; (void)out_size; (void)ws_size;

  k_prep_input<<<(LLX * RBr * FFX) / 256, 256, 0, stream>>>(inp, (u16*)(ws + OFF_ABUF0));
  k_zero<<<2048, 256, 0, stream>>>((uint32_t*)(ws + OFF_HZ), SZ_STATE / 4);
  k_persist<<<NBLOCKS, 512, 0, stream>>>(ws, Wf, Wo, Bias, out);
}